// Round 6
// baseline (441.124 us; speedup 1.0000x reference)
//
#include <hip/hip_runtime.h>

#define M_DIM 256
#define N_DIM 8192
#define K_DIM 8192
#define BN 64
#define BK 32
#define KSPLIT 4
#define KLEN (K_DIM / KSPLIT)   // 2048
#define NT (KLEN / BK)          // 64
#define ABY 16384               // A tile: 256 rows x 32 k x f16
#define BBY 4096                // B tile: 64 rows x 32 k x f16
#define BUFB (ABY + BBY)        // 20480 per buffer, x4 = 80 KB

typedef _Float16 half_t;
typedef __attribute__((ext_vector_type(8))) _Float16 half8;
typedef __attribute__((ext_vector_type(4))) float f32x4;
typedef __attribute__((ext_vector_type(2))) unsigned int u32x2;
typedef __attribute__((ext_vector_type(4))) unsigned int u32x4;

__device__ __forceinline__ unsigned int pk2(float a, float b) {
  // exact for integers |v| <= 2048 (W path); x already RNE-rounded in convert_x
  return __builtin_bit_cast(unsigned int, __builtin_amdgcn_cvt_pkrtz(a, b));
}
__device__ __forceinline__ void gl16(const void* g, void* l) {
  __builtin_amdgcn_global_load_lds(
      (const __attribute__((address_space(1))) unsigned int*)g,
      (__attribute__((address_space(3))) unsigned int*)l, 16, 0, 0);
}

// ---- W int32 [64M] -> int8 [64M] pure sequential stream (~320 MB moved) ----
__global__ __launch_bounds__(256) void compact_w(const int* __restrict__ Wq,
                                                 unsigned int* __restrict__ Wc) {
  const size_t c = (size_t)blockIdx.x * 256 + threadIdx.x;  // 4M threads, 16B out each
  const u32x4* src = (const u32x4*)Wq + c * 4;
  u32x4 a = src[0], b = src[1], d = src[2], e = src[3];
  u32x4 o;
  o.x = (a.x & 0xFF) | ((a.y & 0xFF) << 8) | ((a.z & 0xFF) << 16) | (a.w << 24);
  o.y = (b.x & 0xFF) | ((b.y & 0xFF) << 8) | ((b.z & 0xFF) << 16) | (b.w << 24);
  o.z = (d.x & 0xFF) | ((d.y & 0xFF) << 8) | ((d.z & 0xFF) << 16) | (d.w << 24);
  o.w = (e.x & 0xFF) | ((e.y & 0xFF) << 8) | ((e.z & 0xFF) << 16) | (e.w << 24);
  *((u32x4*)Wc + c) = o;
}

// ---- x f32 [256][8192] -> f16, K-tiled [kt][row][32], chunk-XOR-swizzled ----
// (rule 21: swizzle baked into SOURCE so linear global_load_lds + swizzled read match)
__global__ __launch_bounds__(256) void convert_x(const float* __restrict__ x,
                                                 half_t* __restrict__ xh) {
  const int gid = blockIdx.x * 256 + threadIdx.x;  // 262144
  const int row = gid >> 10;
  const int k0 = (gid & 1023) << 3;
  float4 v0 = *(const float4*)(x + (size_t)row * K_DIM + k0);
  float4 v1 = *(const float4*)(x + (size_t)row * K_DIM + k0 + 4);
  half8 h;
  h[0] = (half_t)v0.x; h[1] = (half_t)v0.y; h[2] = (half_t)v0.z; h[3] = (half_t)v0.w;
  h[4] = (half_t)v1.x; h[5] = (half_t)v1.y; h[6] = (half_t)v1.z; h[7] = (half_t)v1.w;
  const int kt = k0 >> 5;
  const int cx = ((k0 >> 3) & 3) ^ ((row >> 1) & 3);
  *(half8*)(xh + (size_t)kt * 8192 + row * 32 + cx * 8) = h;
}

// ---- out[m][n] += scale * sum_k x[m][k]*W[n][k]  (+bias on ks==0) ----
__global__ __launch_bounds__(512, 4) void qgemm(
    const half_t* __restrict__ xh, const unsigned int* __restrict__ Wc,
    const float* __restrict__ scales, const float* __restrict__ bias,
    float* __restrict__ out) {
  __shared__ __align__(1024) char lds[4 * BUFB];  // 81920 B -> 2 blocks/CU

  const int tid = threadIdx.x;
  const int bid = blockIdx.x;
  const int p = bid & 7;             // XCD (round-robin dispatch)
  const int ks = p >> 1;             // k-quarter: 2 XCDs share a 1MB x-slice (L2)
  const int t = ((bid >> 3) << 1) | (p & 1);  // N-tile 0..127
  const int col0 = t * BN;

  const int wid = tid >> 6, lane = tid & 63;
  const int wm = wid >> 1, wn = wid & 1;       // 4x2 waves, wave tile 64x32
  const int r16 = lane & 15, g4 = lane >> 4;

  const half_t* abase = xh + (size_t)(ks * NT) * 8192;
  // W staging: thread (wr, wc) loads 4 int8 weights (one uint) per tile
  const int wr = tid >> 3, wc = tid & 7;
  // Wc as uint array: row stride = 8192 B = 2048 uints; tile stride = 32 B = 8 uints
  const unsigned int* wp0 = Wc + (size_t)(col0 + wr) * 2048 + ks * 512 + wc;
  const int wlds = ABY + wr * 64 + (((wc >> 1) ^ ((wr >> 1) & 3)) << 4) + ((wc & 1) << 3);

  // fragment read offsets (chunk-XOR swizzle -> 2-way banks, free)
  int aoff[4], boff[2];
#pragma unroll
  for (int mf = 0; mf < 4; ++mf) {
    int ra = wm * 64 + mf * 16 + r16;
    aoff[mf] = ra * 64 + ((g4 ^ ((ra >> 1) & 3)) << 4);
  }
#pragma unroll
  for (int nf = 0; nf < 2; ++nf) {
    int rb = wn * 32 + nf * 16 + r16;
    boff[nf] = ABY + rb * 64 + ((g4 ^ ((rb >> 1) & 3)) << 4);
  }

  f32x4 acc[4][2];
#pragma unroll
  for (int i = 0; i < 4; ++i)
#pragma unroll
    for (int j = 0; j < 2; ++j) acc[i][j] = (f32x4){0.f, 0.f, 0.f, 0.f};

  unsigned int Wset0, Wset1, Wset2, Wset3;

  // int8x4 (packed uint) -> 4 f16 (exact) -> 8B LDS write
#define WRITE_W(WORD, DST)                                                    \
  {                                                                           \
    const int wi = (int)(WORD);                                               \
    u32x2 pb;                                                                 \
    pb.x = pk2((float)(signed char)(wi & 0xFF), (float)(signed char)((wi >> 8) & 0xFF)); \
    pb.y = pk2((float)(signed char)((wi >> 16) & 0xFF), (float)(wi >> 24));   \
    *(u32x2*)(DST) = pb;                                                      \
  }

  // ---- prologue: issue order L(0) G(0)x2 L(1) G(1)x2 L(2), pinned ----
  Wset0 = *wp0;
  __builtin_amdgcn_sched_barrier(0);
  gl16(abase + tid * 8, lds + tid * 16);
  gl16(abase + 4096 + tid * 8, lds + 8192 + tid * 16);
  __builtin_amdgcn_sched_barrier(0);
  Wset1 = *(wp0 + 8);
  __builtin_amdgcn_sched_barrier(0);
  gl16(abase + 8192 + tid * 8, lds + BUFB + tid * 16);
  gl16(abase + 8192 + 4096 + tid * 8, lds + BUFB + 8192 + tid * 16);
  __builtin_amdgcn_sched_barrier(0);
  Wset2 = *(wp0 + 16);
  __builtin_amdgcn_sched_barrier(0);
  asm volatile("s_waitcnt vmcnt(6)" ::: "memory");  // W(0) ready
  WRITE_W(Wset0, lds + wlds)
  __builtin_amdgcn_sched_barrier(0);
  asm volatile("s_waitcnt vmcnt(4) lgkmcnt(0)" ::: "memory");  // A(0) staged
  __builtin_amdgcn_s_barrier();
  __builtin_amdgcn_sched_barrier(0);

  // per iter KT: top wait W(KT+1)[issued KT-2]; ds_write it; gl16 A(KT+2);
  // load W(KT+3); compute buf[KT&3]; end wait A(KT+1) done; barrier.
#define ONE_ITER(KT, C0, C1, C2, C3)                                          \
  {                                                                           \
    asm volatile("s_waitcnt vmcnt(3)" ::: "memory");                          \
    __builtin_amdgcn_sched_barrier(0);                                        \
    WRITE_W(Wset##C1, lds + (C1)*BUFB + wlds)                                 \
    __builtin_amdgcn_sched_barrier(0);                                        \
    {                                                                         \
      const int an = ((KT) + 2 < NT) ? (KT) + 2 : NT - 1;                     \
      const half_t* asrc = abase + (size_t)an * 8192;                         \
      gl16(asrc + tid * 8, lds + (C2)*BUFB + tid * 16);                       \
      gl16(asrc + 4096 + tid * 8, lds + (C2)*BUFB + 8192 + tid * 16);         \
    }                                                                         \
    __builtin_amdgcn_sched_barrier(0);                                        \
    {                                                                         \
      const int w3 = ((KT) + 3 < NT) ? (KT) + 3 : NT - 1;                     \
      Wset##C3 = *(wp0 + (size_t)w3 * 8);                                     \
    }                                                                         \
    __builtin_amdgcn_sched_barrier(0);                                        \
    {                                                                         \
      const char* Bc = lds + (C0)*BUFB;                                       \
      half8 af0 = *(const half8*)(Bc + aoff[0]);                              \
      half8 af1 = *(const half8*)(Bc + aoff[1]);                              \
      half8 af2 = *(const half8*)(Bc + aoff[2]);                              \
      half8 af3 = *(const half8*)(Bc + aoff[3]);                              \
      half8 bf0 = *(const half8*)(Bc + boff[0]);                              \
      half8 bf1 = *(const half8*)(Bc + boff[1]);                              \
      acc[0][0] = __builtin_amdgcn_mfma_f32_16x16x32_f16(af0, bf0, acc[0][0], 0, 0, 0); \
      acc[0][1] = __builtin_amdgcn_mfma_f32_16x16x32_f16(af0, bf1, acc[0][1], 0, 0, 0); \
      acc[1][0] = __builtin_amdgcn_mfma_f32_16x16x32_f16(af1, bf0, acc[1][0], 0, 0, 0); \
      acc[1][1] = __builtin_amdgcn_mfma_f32_16x16x32_f16(af1, bf1, acc[1][1], 0, 0, 0); \
      acc[2][0] = __builtin_amdgcn_mfma_f32_16x16x32_f16(af2, bf0, acc[2][0], 0, 0, 0); \
      acc[2][1] = __builtin_amdgcn_mfma_f32_16x16x32_f16(af2, bf1, acc[2][1], 0, 0, 0); \
      acc[3][0] = __builtin_amdgcn_mfma_f32_16x16x32_f16(af3, bf0, acc[3][0], 0, 0, 0); \
      acc[3][1] = __builtin_amdgcn_mfma_f32_16x16x32_f16(af3, bf1, acc[3][1], 0, 0, 0); \
    }                                                                         \
    __builtin_amdgcn_sched_barrier(0);                                        \
    asm volatile("s_waitcnt vmcnt(4) lgkmcnt(0)" ::: "memory");               \
    __builtin_amdgcn_s_barrier();                                             \
    __builtin_amdgcn_sched_barrier(0);                                        \
  }

  for (int kt0 = 0; kt0 < NT; kt0 += 4) {
    ONE_ITER(kt0 + 0, 0, 1, 2, 3)
    ONE_ITER(kt0 + 1, 1, 2, 3, 0)
    ONE_ITER(kt0 + 2, 2, 3, 0, 1)
    ONE_ITER(kt0 + 3, 3, 0, 1, 2)
  }
#undef ONE_ITER
#undef WRITE_W

  // ---- epilogue: scale, bias (ks==0), atomic k-split accumulate ----
  const float scale = scales[0];
#pragma unroll
  for (int nf = 0; nf < 2; ++nf) {
    const int gcol = col0 + wn * 32 + nf * 16 + r16;
    const float bv = (ks == 0) ? bias[gcol] : 0.0f;
#pragma unroll
    for (int mf = 0; mf < 4; ++mf) {
      const int grow0 = wm * 64 + mf * 16 + g4 * 4;
#pragma unroll
      for (int j = 0; j < 4; ++j) {
        atomicAdd(out + (size_t)(grow0 + j) * N_DIM + gcol,
                  scale * acc[mf][nf][j] + bv);
      }
    }
  }
}

extern "C" void kernel_launch(void* const* d_in, const int* in_sizes, int n_in,
                              void* d_out, int out_size, void* d_ws, size_t ws_size,
                              hipStream_t stream) {
  const float* x = (const float*)d_in[0];
  const int* Wq = (const int*)d_in[1];  // int8 weights widened to int32
  const float* scales = (const float*)d_in[2];
  const float* bias = (const float*)d_in[3];
  float* out = (float*)d_out;

  half_t* xh = (half_t*)d_ws;                                   // [0, 4 MB)
  unsigned int* Wcomp = (unsigned int*)((char*)d_ws + (4u << 20));  // [4 MB, 68 MB)

  hipMemsetAsync(d_out, 0, (size_t)M_DIM * N_DIM * sizeof(float), stream);
  convert_x<<<dim3(1024), dim3(256), 0, stream>>>(x, xh);
  compact_w<<<dim3(16384), dim3(256), 0, stream>>>(Wq, Wcomp);
  qgemm<<<dim3(512), dim3(512), 0, stream>>>(xh, Wcomp, scales, bias, out);
}